// Round 16
// baseline (250.321 us; speedup 1.0000x reference)
//
#include <hip/hip_runtime.h>

#define NN 100000
#define EPS 1e-5f

// ---- workspace layout (4-byte units), ~83MB total ----
static const size_t OFF_ROWST  = 0;           // rowstart [100k]
static const size_t OFF_ROWEN  = 100000;      // rowend   [100k]
static const size_t OFF_ADJ    = 200000;      // adj [256*10496] -> 2,886,976
static const size_t OFF_AGG1   = 2886976;     // N*32 f32 -> 6,086,976
static const size_t OFF_AGG2   = 6086976;     // N*64 f32 -> 12,486,976
static const size_t OFF_PAIRS  = 2886976;     // u32 aliases agg (dead before agg1)
static const size_t OFF_XB     = 12486976;    // N*32 bf16 -> 14,086,976
static const size_t OFF_Z1B    = 0;           // N*128 bf16 = 6.4M floats (region dead by fc1)
static const size_t OFF_H1B    = 14086976;    // N*64 bf16 -> 17,286,976
static const size_t OFF_Z2B    = 14086976;    // aliases h1b (dead before fc2) -> 17,286,976
static const size_t OFF_WSPL   = 20487000;    // 57,344 ushorts -> 20,515,672
static const size_t OFF_BUKCNT = 20515712;    // 256 ints
static const size_t OFF_STATS1 = 20515968;    // 128 slots * 256 -> 20,548,736
static const size_t OFF_STATS2 = 20548736;    // 128 slots * 128 -> 20,565,120
static const size_t OFF_COEF1  = 20565120;    // 256
static const size_t OFF_COEF2  = 20565376;    // 128
static const size_t OFF_BHIST  = 20565504;    // NCH*256 ints -> 20,765,696
static const size_t ZERO_START = 20515968;    // slotted stats only
static const size_t ZERO_INTS  = 49152;

#define NSLOT 128

// split-weight plane offsets (ushort units within WSPL)
#define WL1_HI 0
#define WL1_LO 2048
#define WR1_HI 4096
#define WR1_LO 6144
#define WL2_HI 8192
#define WL2_LO 12288
#define WR2_HI 16384
#define WR2_LO 20480
#define F1_HI  24576
#define F1_LO  32768
#define F2_HI  40960
#define F2_LO  49152

#define NBUK 256
#define BSHIFT 9
#define BCAP 10496
#define CHUNK 2048

typedef __attribute__((ext_vector_type(8))) short short8;
typedef __attribute__((ext_vector_type(4))) float f32x4;

#define MFMA_16x16x32(a, b, c) __builtin_amdgcn_mfma_f32_16x16x32_bf16(a, b, c, 0, 0, 0)

__device__ inline unsigned short f2bf(float f) {
  unsigned u = __builtin_bit_cast(unsigned, f);
  unsigned r = (u + 0x7fffu + ((u >> 16) & 1u)) >> 16;
  return (unsigned short)r;
}
__device__ inline float bf2f(unsigned short h) {
  unsigned u = ((unsigned)h) << 16;
  return __builtin_bit_cast(float, u);
}

// load 8 contiguous values (f32 or bf16 per BFIN; optional BN+relu), split hi/lo bf16
template<bool BNIN, bool BFIN>
__device__ inline void load_split(const void* __restrict__ p,
                                  const float* __restrict__ ca,
                                  const float* __restrict__ cc,
                                  short8& hi, short8& lo) {
  #pragma unroll
  for (int j = 0; j < 8; ++j) {
    float v = BFIN ? bf2f(((const unsigned short*)p)[j]) : ((const float*)p)[j];
    if (BNIN) v = fmaxf(v * ca[j] + cc[j], 0.f);
    unsigned short h = f2bf(v);
    hi[j] = (short)h;
    lo[j] = (short)f2bf(v - bf2f(h));
  }
}

// ---- one-shot: split all 6 weight matrices into hi/lo bf16 planes ----
struct WsplitArgs {
  const float* src[6];
  unsigned short* dhi[6];
  unsigned short* dlo[6];
  int n[6];
};
__global__ __launch_bounds__(256) void wsplit_k(WsplitArgs a) {
  int m = blockIdx.y;
  int n = a.n[m];
  for (int i = blockIdx.x * 256 + threadIdx.x; i < n; i += gridDim.x * 256) {
    float v = a.src[m][i];
    unsigned short h = f2bf(v);
    a.dhi[m][i] = h;
    a.dlo[m][i] = f2bf(v - bf2f(h));
  }
}

// ---- convert f32 plane -> bf16 plane ----
__global__ __launch_bounds__(256) void cvt_bf_k(const float* __restrict__ in,
                                                unsigned short* __restrict__ out,
                                                int n8) {
  int t = blockIdx.x * 256 + threadIdx.x;
  if (t >= n8) return;
  const float4* p = (const float4*)(in + (size_t)t * 8);
  float4 a = p[0], b = p[1];
  ushort4 u0, u1;
  u0.x = f2bf(a.x); u0.y = f2bf(a.y); u0.z = f2bf(a.z); u0.w = f2bf(a.w);
  u1.x = f2bf(b.x); u1.y = f2bf(b.y); u1.z = f2bf(b.z); u1.w = f2bf(b.w);
  ((ushort4*)(out + (size_t)t * 8))[0] = u0;
  ((ushort4*)(out + (size_t)t * 8))[1] = u1;
}

// ---- build A: per-chunk bucket histogram ----
__global__ __launch_bounds__(256) void hista_k(const int* __restrict__ ei, int E,
                                               int* __restrict__ blockhist) {
  __shared__ int h[NBUK];
  int tid = threadIdx.x;
  h[tid] = 0;
  __syncthreads();
  int lo = blockIdx.x * CHUNK, hi = min(lo + CHUNK, E);
  for (int e = lo + tid; e < hi; e += 256) {
    int t = ei[E + e];
    if ((unsigned)t < NN) atomicAdd(&h[t >> BSHIFT], 1);
  }
  __syncthreads();
  blockhist[(size_t)blockIdx.x * NBUK + tid] = h[tid];
}

// ---- build B: per-bucket exclusive scan over chunks + totals ----
__global__ __launch_bounds__(256) void scanb_k(int* __restrict__ blockhist, int nch,
                                               int* __restrict__ bukcnt) {
  __shared__ int sh[256];
  int b = blockIdx.x, t = threadIdx.x;
  int run = 0;
  for (int base = 0; base < nch; base += 256) {
    int c = base + t;
    int v = (c < nch) ? blockhist[(size_t)c * NBUK + b] : 0;
    sh[t] = v;
    __syncthreads();
    for (int o = 1; o < 256; o <<= 1) {
      int u = (t >= o) ? sh[t - o] : 0;
      __syncthreads();
      sh[t] += u;
      __syncthreads();
    }
    if (c < nch) blockhist[(size_t)c * NBUK + b] = run + sh[t] - v;
    int tot = sh[255];
    __syncthreads();
    run += tot;
  }
  if (t == 0) bukcnt[b] = run;
}

// ---- build C: scatter edges into packed bucket pairs (LDS cursors only) ----
__global__ __launch_bounds__(256) void scat_k(const int* __restrict__ ei, int E,
                                              const int* __restrict__ blockhist,
                                              unsigned* __restrict__ pairs) {
  __shared__ int wb[NBUK], cur[NBUK];
  int tid = threadIdx.x;
  wb[tid] = blockhist[(size_t)blockIdx.x * NBUK + tid];
  cur[tid] = 0;
  __syncthreads();
  int lo = blockIdx.x * CHUNK, hi = min(lo + CHUNK, E);
  for (int e = lo + tid; e < hi; e += 256) {
    int s = ei[e], t = ei[E + e];
    if ((unsigned)t >= NN) continue;
    if ((unsigned)s >= NN) s = 0;
    int b = t >> BSHIFT;
    int off = atomicAdd(&cur[b], 1);
    pairs[(size_t)b * BCAP + wb[b] + off] = ((unsigned)s << 9) | (unsigned)(t & 511);
  }
}

// ---- build D: per-bucket hist + scan -> rowstart/rowend + adj fill ----
__global__ __launch_bounds__(256) void bfill2_k(const unsigned* __restrict__ pairs,
                                                const int* __restrict__ bukcnt,
                                                int* __restrict__ rowstart,
                                                int* __restrict__ rowend,
                                                int* __restrict__ adj) {
  __shared__ int d[512];
  __shared__ int part[256];
  int b = blockIdx.x;
  int t = threadIdx.x;
  int base = b * BCAP, cnt = bukcnt[b];
  d[t] = 0; d[t + 256] = 0;
  __syncthreads();
  for (int p = base + t; p < base + cnt; p += 256)
    atomicAdd(&d[pairs[p] & 511], 1);
  __syncthreads();
  int d0 = d[2 * t], d1 = d[2 * t + 1];
  part[t] = d0 + d1;
  __syncthreads();
  for (int o = 1; o < 256; o <<= 1) {
    int u = (t >= o) ? part[t - o] : 0;
    __syncthreads();
    part[t] += u;
    __syncthreads();
  }
  int e0 = (t > 0) ? part[t - 1] : 0;
  int e1 = e0 + d0;
  d[2 * t] = e0;
  d[2 * t + 1] = e1;
  int n0 = (b << BSHIFT) + 2 * t;
  if (n0 < NN)     { rowstart[n0]     = base + e0; rowend[n0]     = base + e1; }
  if (n0 + 1 < NN) { rowstart[n0 + 1] = base + e1; rowend[n0 + 1] = base + e1 + d1; }
  __syncthreads();
  for (int p = base + t; p < base + cnt; p += 256) {
    unsigned pr = pairs[p];
    int pos = atomicAdd(&d[pr & 511], 1);
    adj[base + pos] = (int)(pr >> 9);
  }
}

// ---- gather-side mean aggregation, ushort4-vectorized ----
template<int K>
__global__ __launch_bounds__(256) void aggregate_bf(const unsigned short* __restrict__ xb,
                                                    const int* __restrict__ rowstart,
                                                    const int* __restrict__ rowend,
                                                    const int* __restrict__ adj,
                                                    float* __restrict__ agg) {
  constexpr int GL = K / 4;
  constexpr int NPB = 256 / GL;
  int lg = threadIdx.x & (GL - 1);
  int node = blockIdx.x * NPB + (threadIdx.x / GL);
  if (node >= NN) return;
  int s0 = rowstart[node], s1 = rowend[node];
  float4 a0 = {0,0,0,0}, a1 = {0,0,0,0}, a2 = {0,0,0,0}, a3 = {0,0,0,0};
  int e = s0;
  for (; e + 3 < s1; e += 4) {
    int i0 = adj[e], i1 = adj[e+1], i2 = adj[e+2], i3 = adj[e+3];
    ushort4 u0 = *(const ushort4*)(xb + (size_t)i0 * K + lg * 4);
    ushort4 u1 = *(const ushort4*)(xb + (size_t)i1 * K + lg * 4);
    ushort4 u2 = *(const ushort4*)(xb + (size_t)i2 * K + lg * 4);
    ushort4 u3 = *(const ushort4*)(xb + (size_t)i3 * K + lg * 4);
    a0.x += bf2f(u0.x); a0.y += bf2f(u0.y); a0.z += bf2f(u0.z); a0.w += bf2f(u0.w);
    a1.x += bf2f(u1.x); a1.y += bf2f(u1.y); a1.z += bf2f(u1.z); a1.w += bf2f(u1.w);
    a2.x += bf2f(u2.x); a2.y += bf2f(u2.y); a2.z += bf2f(u2.z); a2.w += bf2f(u2.w);
    a3.x += bf2f(u3.x); a3.y += bf2f(u3.y); a3.z += bf2f(u3.z); a3.w += bf2f(u3.w);
  }
  for (; e < s1; ++e) {
    ushort4 u = *(const ushort4*)(xb + (size_t)adj[e] * K + lg * 4);
    a0.x += bf2f(u.x); a0.y += bf2f(u.y); a0.z += bf2f(u.z); a0.w += bf2f(u.w);
  }
  float inv = 1.0f / fmaxf((float)(s1 - s0), 1.0f);
  float4 r;
  r.x = (a0.x + a1.x + a2.x + a3.x) * inv;
  r.y = (a0.y + a1.y + a2.y + a3.y) * inv;
  r.z = (a0.z + a1.z + a2.z + a3.z) * inv;
  r.w = (a0.w + a1.w + a2.w + a3.w) * inv;
  *(float4*)(agg + (size_t)node * K + lg * 4) = r;
}

// ---- MFMA dense layer; 128 rows/block (2 row-tiles/wave), weights in LDS ----
// BFIN: A-input is bf16 plane (inAb). FOUT: write f32 out. BFOUT: write bf16 outb.
template<int K, int C, bool SAGE, bool BNIN, bool BFIN, bool RELU, bool FOUT,
         bool BFOUT, bool STATS>
__global__ __launch_bounds__(256) void mfma_dense(const float* __restrict__ inA,
                                                  const unsigned short* __restrict__ inAb,
                                                  const float* __restrict__ inB,
                                                  const unsigned short* __restrict__ whiA,
                                                  const unsigned short* __restrict__ wloA,
                                                  const unsigned short* __restrict__ whiB,
                                                  const unsigned short* __restrict__ wloB,
                                                  const float* __restrict__ bias,
                                                  const float* __restrict__ coef,
                                                  float* __restrict__ out,
                                                  unsigned short* __restrict__ outb,
                                                  float* __restrict__ stats) {
  constexpr int KF = K / 32;
  constexpr int KC = K / 8;
  constexpr int SWZ = (KC < 8 ? KC : 8) - 1;
  __shared__ unsigned short swhiA[C * K], swloA[C * K];
  __shared__ unsigned short swhiB[SAGE ? C * K : 8], swloB[SAGE ? C * K : 8];
  __shared__ float ls[STATS ? C : 1], lq[STATS ? C : 1];

  int tid = threadIdx.x;
  for (int i = tid; i < C * KC; i += 256) {
    int col = i / KC, c = i % KC;
    int pos = col * KC + (c ^ (col & SWZ));
    ((short8*)swhiA)[pos] = ((const short8*)whiA)[i];
    ((short8*)swloA)[pos] = ((const short8*)wloA)[i];
    if (SAGE) {
      ((short8*)swhiB)[pos] = ((const short8*)whiB)[i];
      ((short8*)swloB)[pos] = ((const short8*)wloB)[i];
    }
  }
  if (STATS) {
    for (int i = tid; i < C; i += 256) { ls[i] = 0.f; lq[i] = 0.f; }
  }
  __syncthreads();

  int wid  = tid >> 6;
  int lane = tid & 63;
  int r = lane & 15, g = lane >> 4;
  int koff = g * 8;

  #pragma unroll 1
  for (int tl = 0; tl < 2; ++tl) {
    int row0 = blockIdx.x * 128 + tl * 64 + wid * 16;
    int arow = row0 + r; if (arow > NN - 1) arow = NN - 1;   // clamp tail reads

    short8 ahi[KF], alo[KF];
    short8 a2hi[SAGE ? KF : 1], a2lo[SAGE ? KF : 1];
    #pragma unroll
    for (int kf = 0; kf < KF; ++kf) {
      const void* p = BFIN
          ? (const void*)(inAb + (size_t)arow * K + kf * 32 + koff)
          : (const void*)(inA  + (size_t)arow * K + kf * 32 + koff);
      load_split<BNIN, BFIN>(p, coef + kf * 32 + koff, coef + K + kf * 32 + koff,
                             ahi[kf], alo[kf]);
    }
    if (SAGE) {
      #pragma unroll
      for (int kf = 0; kf < KF; ++kf) {
        const float* p = inB + (size_t)arow * K + kf * 32 + koff;
        load_split<false, false>(p, nullptr, nullptr, a2hi[kf], a2lo[kf]);
      }
    }

    #pragma unroll
    for (int cf = 0; cf < C / 16; ++cf) {
      int col = cf * 16 + r;
      float bv = bias[col];
      f32x4 acc = {bv, bv, bv, bv};
      #pragma unroll
      for (int kf = 0; kf < KF; ++kf) {
        int c = kf * 4 + g;
        int pos = col * KC + (c ^ (col & SWZ));
        short8 whi = ((const short8*)swhiA)[pos];
        short8 wlo = ((const short8*)swloA)[pos];
        acc = MFMA_16x16x32(ahi[kf], whi, acc);
        acc = MFMA_16x16x32(ahi[kf], wlo, acc);
        acc = MFMA_16x16x32(alo[kf], whi, acc);
        if (SAGE) {
          short8 vhi = ((const short8*)swhiB)[pos];
          short8 vlo = ((const short8*)swloB)[pos];
          acc = MFMA_16x16x32(a2hi[kf], vhi, acc);
          acc = MFMA_16x16x32(a2hi[kf], vlo, acc);
          acc = MFMA_16x16x32(a2lo[kf], vhi, acc);
        }
      }
      if (STATS) {
        float s = 0.f, q = 0.f;
        #pragma unroll
        for (int j = 0; j < 4; ++j) {
          if (row0 + g * 4 + j < NN) {
            float v = acc[j];
            s += v; q += v * v;
          }
        }
        s += __shfl_xor(s, 16, 64); s += __shfl_xor(s, 32, 64);
        q += __shfl_xor(q, 16, 64); q += __shfl_xor(q, 32, 64);
        if (g == 0) { atomicAdd(&ls[col], s); atomicAdd(&lq[col], q); }
      }
      #pragma unroll
      for (int j = 0; j < 4; ++j) {
        int orow = row0 + g * 4 + j;
        if (orow < NN) {
          float v = acc[j];
          if (RELU) v = fmaxf(v, 0.f);
          if (FOUT)  out[(size_t)orow * C + col] = v;
          if (BFOUT) outb[(size_t)orow * C + col] = f2bf(v);
        }
      }
    }
  }
  if (STATS) {
    __syncthreads();
    float* sl = stats + (size_t)(blockIdx.x & (NSLOT - 1)) * 2 * C;
    for (int i = tid; i < C; i += 256) {
      atomicAdd(&sl[i], ls[i]);
      atomicAdd(&sl[C + i], lq[i]);
    }
  }
}

// ---- slotted stats -> affine coefs ----
__global__ void bncoef(const float* __restrict__ stats, const float* __restrict__ g,
                       const float* __restrict__ b, float* __restrict__ coef, int C) {
  int j = threadIdx.x;
  if (j >= C) return;
  float s = 0.f, q = 0.f;
  for (int sl = 0; sl < NSLOT; ++sl) {
    s += stats[(size_t)sl * 2 * C + j];
    q += stats[(size_t)sl * 2 * C + C + j];
  }
  float mu  = s * (1.0f / NN);
  float var = q * (1.0f / NN) - mu * mu;
  float a = g[j] * rsqrtf(var + EPS);
  coef[j] = a;
  coef[C + j] = b[j] - mu * a;
}

// ---- final: out[i] = sum_j relu(bf2f(z2b[i][j])*a+c) * fc3w[j] + fc3b ----
__global__ __launch_bounds__(256) void final_k(const unsigned short* __restrict__ z2b,
                                               const float* __restrict__ coef,
                                               const float* __restrict__ fc3w,
                                               const float* __restrict__ fc3b,
                                               float* __restrict__ out) {
  int t = blockIdx.x * 256 + threadIdx.x;
  int i = t >> 6;
  int j = t & 63;
  if (i >= NN) return;
  float v = bf2f(z2b[(size_t)i * 64 + j]);
  float p = fmaxf(v * coef[j] + coef[64 + j], 0.f) * fc3w[j];
  #pragma unroll
  for (int o = 32; o > 0; o >>= 1) p += __shfl_xor(p, o, 64);
  if (j == 0) out[i] = p + fc3b[0];
}

extern "C" void kernel_launch(void* const* d_in, const int* in_sizes, int n_in,
                              void* d_out, int out_size, void* d_ws, size_t ws_size,
                              hipStream_t stream) {
  const float* x     = (const float*)d_in[0];
  const int*   ei    = (const int*)d_in[1];
  const float* w_l1  = (const float*)d_in[2];
  const float* b_l1  = (const float*)d_in[3];
  const float* w_r1  = (const float*)d_in[4];
  const float* w_l2  = (const float*)d_in[5];
  const float* b_l2  = (const float*)d_in[6];
  const float* w_r2  = (const float*)d_in[7];
  const float* fc1_w = (const float*)d_in[8];
  const float* fc1_b = (const float*)d_in[9];
  const float* bn1_g = (const float*)d_in[10];
  const float* bn1_b = (const float*)d_in[11];
  const float* fc2_w = (const float*)d_in[12];
  const float* fc2_b = (const float*)d_in[13];
  const float* bn2_g = (const float*)d_in[14];
  const float* bn2_b = (const float*)d_in[15];
  const float* fc3_w = (const float*)d_in[16];
  const float* fc3_b = (const float*)d_in[17];

  const int E = in_sizes[1] / 2;

  float* ws       = (float*)d_ws;
  int*   rowstart = (int*)(ws + OFF_ROWST);
  int*   rowend   = (int*)(ws + OFF_ROWEN);
  int*   adj      = (int*)(ws + OFF_ADJ);
  float* agg1     = ws + OFF_AGG1;
  float* agg2     = ws + OFF_AGG2;
  unsigned short* xb  = (unsigned short*)(ws + OFF_XB);
  unsigned short* h1b = (unsigned short*)(ws + OFF_H1B);
  unsigned short* z1b = (unsigned short*)(ws + OFF_Z1B);
  unsigned short* z2b = (unsigned short*)(ws + OFF_Z2B);
  int*   bukcnt   = (int*)(ws + OFF_BUKCNT);
  float* stats1   = ws + OFF_STATS1;
  float* stats2   = ws + OFF_STATS2;
  float* coef1    = ws + OFF_COEF1;
  float* coef2    = ws + OFF_COEF2;
  unsigned* pairs = (unsigned*)(ws + OFF_PAIRS);
  int*   bhist    = (int*)(ws + OFF_BHIST);
  unsigned short* wspl = (unsigned short*)(ws + OFF_WSPL);

  float* outv = (float*)d_out;             // [NN]
  float* h1   = outv + NN;                 // [NN,64]
  float* h2   = h1 + (size_t)NN * 64;      // [NN,64]

  hipMemsetAsync(ws + ZERO_START, 0, ZERO_INTS * sizeof(float), stream);

  // one-shot weight splits (hi/lo bf16 planes)
  WsplitArgs wa;
  wa.src[0] = w_l1;  wa.dhi[0] = wspl + WL1_HI; wa.dlo[0] = wspl + WL1_LO; wa.n[0] = 64 * 32;
  wa.src[1] = w_r1;  wa.dhi[1] = wspl + WR1_HI; wa.dlo[1] = wspl + WR1_LO; wa.n[1] = 64 * 32;
  wa.src[2] = w_l2;  wa.dhi[2] = wspl + WL2_HI; wa.dlo[2] = wspl + WL2_LO; wa.n[2] = 64 * 64;
  wa.src[3] = w_r2;  wa.dhi[3] = wspl + WR2_HI; wa.dlo[3] = wspl + WR2_LO; wa.n[3] = 64 * 64;
  wa.src[4] = fc1_w; wa.dhi[4] = wspl + F1_HI;  wa.dlo[4] = wspl + F1_LO;  wa.n[4] = 128 * 64;
  wa.src[5] = fc2_w; wa.dhi[5] = wspl + F2_HI;  wa.dlo[5] = wspl + F2_LO;  wa.n[5] = 64 * 128;
  wsplit_k<<<dim3(8, 6), 256, 0, stream>>>(wa);

  // bf16 copy of x for cheap gathering
  cvt_bf_k<<<(NN * 32 / 8 + 255) / 256, 256, 0, stream>>>(x, xb, NN * 32 / 8);

  // CSR build — deterministic partition
  const int NCH = (E + CHUNK - 1) / CHUNK;
  hista_k<<<NCH, 256, 0, stream>>>(ei, E, bhist);
  scanb_k<<<NBUK, 256, 0, stream>>>(bhist, NCH, bukcnt);
  scat_k<<<NCH, 256, 0, stream>>>(ei, E, bhist, pairs);
  bfill2_k<<<NBUK, 256, 0, stream>>>(pairs, bukcnt, rowstart, rowend, adj);

  const int MB = (NN + 127) / 128;   // 128 rows per block

  // layer 1
  aggregate_bf<32><<<(NN + 31) / 32, 256, 0, stream>>>(xb, rowstart, rowend, adj, agg1);
  mfma_dense<32, 64, true, false, false, true, true, true, false><<<MB, 256, 0, stream>>>(
      agg1, nullptr, x, wspl + WL1_HI, wspl + WL1_LO, wspl + WR1_HI, wspl + WR1_LO,
      b_l1, nullptr, h1, h1b, nullptr);

  // layer 2
  aggregate_bf<64><<<(NN + 15) / 16, 256, 0, stream>>>(h1b, rowstart, rowend, adj, agg2);
  mfma_dense<64, 64, true, false, false, true, true, false, false><<<MB, 256, 0, stream>>>(
      agg2, nullptr, h1, wspl + WL2_HI, wspl + WL2_LO, wspl + WR2_HI, wspl + WR2_LO,
      b_l2, nullptr, h2, nullptr, nullptr);

  // fc1 -> z1b (bf16, pre-BN) with fused slotted stats
  mfma_dense<64, 128, false, false, false, false, false, true, true><<<MB, 256, 0, stream>>>(
      h2, nullptr, nullptr, wspl + F1_HI, wspl + F1_LO, nullptr, nullptr,
      fc1_b, nullptr, nullptr, z1b, stats1);
  bncoef<<<1, 128, 0, stream>>>(stats1, bn1_g, bn1_b, coef1, 128);

  // fc2 (bf16 input, fused bn1+relu) -> z2b (bf16, pre-BN) with fused stats
  mfma_dense<128, 64, false, true, true, false, false, true, true><<<MB, 256, 0, stream>>>(
      nullptr, z1b, nullptr, wspl + F2_HI, wspl + F2_LO, nullptr, nullptr,
      fc2_b, coef1, nullptr, z2b, stats2);
  bncoef<<<1, 64, 0, stream>>>(stats2, bn2_g, bn2_b, coef2, 64);

  // bn2 + relu + fc3 fused
  final_k<<<(NN * 64 + 255) / 256, 256, 0, stream>>>(z2b, coef2, fc3_w, fc3_b, outv);
}

// Round 17
// 237.837 us; speedup vs baseline: 1.0525x; 1.0525x over previous
//
#include <hip/hip_runtime.h>

#define NN 100000
#define EPS 1e-5f

// ---- workspace layout (4-byte units), ~83MB total ----
static const size_t OFF_ROWST  = 0;           // rowstart [100k]
static const size_t OFF_ROWEN  = 100000;      // rowend   [100k]
static const size_t OFF_ADJ    = 200000;      // adj [256*10496] -> 2,886,976
static const size_t OFF_AGG1   = 2886976;     // N*32 f32 -> 6,086,976
static const size_t OFF_AGG2   = 6086976;     // N*64 f32 -> 12,486,976
static const size_t OFF_PAIRS  = 2886976;     // u32 aliases agg (dead before agg1)
static const size_t OFF_XB     = 12486976;    // N*32 bf16 -> 14,086,976
static const size_t OFF_Z1B    = 0;           // N*128 bf16 = 6.4M floats (dead by fc1's input h2)
static const size_t OFF_H1B    = 14086976;    // N*64 bf16 -> 17,286,976
static const size_t OFF_Z2B    = 14086976;    // aliases h1b (dead before fc2) -> 17,286,976
static const size_t OFF_WSPL   = 20487000;    // 57,344 ushorts -> 20,515,672
static const size_t OFF_BUKCNT = 20515712;    // 256 ints
static const size_t OFF_STATS1 = 20515968;    // 128 slots * 256 -> 20,548,736
static const size_t OFF_STATS2 = 20548736;    // 128 slots * 128 -> 20,565,120
static const size_t OFF_COEF1  = 20565120;    // 256
static const size_t OFF_COEF2  = 20565376;    // 128
static const size_t OFF_BHIST  = 20565504;    // NCH*256 ints -> 20,765,696
static const size_t ZERO_START = 20515968;    // slotted stats only
static const size_t ZERO_INTS  = 49152;

#define NSLOT 128

// split-weight plane offsets (ushort units within WSPL)
#define WL1_HI 0
#define WL1_LO 2048
#define WR1_HI 4096
#define WR1_LO 6144
#define WL2_HI 8192
#define WL2_LO 12288
#define WR2_HI 16384
#define WR2_LO 20480
#define F1_HI  24576
#define F1_LO  32768
#define F2_HI  40960
#define F2_LO  49152

#define NBUK 256
#define BSHIFT 9
#define BCAP 10496
#define CHUNK 2048

typedef __attribute__((ext_vector_type(8))) short short8;
typedef __attribute__((ext_vector_type(4))) float f32x4;

#define MFMA_16x16x32(a, b, c) __builtin_amdgcn_mfma_f32_16x16x32_bf16(a, b, c, 0, 0, 0)

__device__ inline unsigned short f2bf(float f) {
  unsigned u = __builtin_bit_cast(unsigned, f);
  unsigned r = (u + 0x7fffu + ((u >> 16) & 1u)) >> 16;
  return (unsigned short)r;
}
__device__ inline float bf2f(unsigned short h) {
  unsigned u = ((unsigned)h) << 16;
  return __builtin_bit_cast(float, u);
}

// load 8 contiguous values (f32 or bf16 per BFIN; optional BN+relu), split hi/lo bf16
template<bool BNIN, bool BFIN>
__device__ inline void load_split(const void* __restrict__ p,
                                  const float* __restrict__ ca,
                                  const float* __restrict__ cc,
                                  short8& hi, short8& lo) {
  #pragma unroll
  for (int j = 0; j < 8; ++j) {
    float v = BFIN ? bf2f(((const unsigned short*)p)[j]) : ((const float*)p)[j];
    if (BNIN) v = fmaxf(v * ca[j] + cc[j], 0.f);
    unsigned short h = f2bf(v);
    hi[j] = (short)h;
    lo[j] = (short)f2bf(v - bf2f(h));
  }
}

// ---- one-shot: split all 6 weight matrices into hi/lo bf16 planes ----
struct WsplitArgs {
  const float* src[6];
  unsigned short* dhi[6];
  unsigned short* dlo[6];
  int n[6];
};
__global__ __launch_bounds__(256) void wsplit_k(WsplitArgs a) {
  int m = blockIdx.y;
  int n = a.n[m];
  for (int i = blockIdx.x * 256 + threadIdx.x; i < n; i += gridDim.x * 256) {
    float v = a.src[m][i];
    unsigned short h = f2bf(v);
    a.dhi[m][i] = h;
    a.dlo[m][i] = f2bf(v - bf2f(h));
  }
}

// ---- convert f32 plane -> bf16 plane ----
__global__ __launch_bounds__(256) void cvt_bf_k(const float* __restrict__ in,
                                                unsigned short* __restrict__ out,
                                                int n8) {
  int t = blockIdx.x * 256 + threadIdx.x;
  if (t >= n8) return;
  const float4* p = (const float4*)(in + (size_t)t * 8);
  float4 a = p[0], b = p[1];
  ushort4 u0, u1;
  u0.x = f2bf(a.x); u0.y = f2bf(a.y); u0.z = f2bf(a.z); u0.w = f2bf(a.w);
  u1.x = f2bf(b.x); u1.y = f2bf(b.y); u1.z = f2bf(b.z); u1.w = f2bf(b.w);
  ((ushort4*)(out + (size_t)t * 8))[0] = u0;
  ((ushort4*)(out + (size_t)t * 8))[1] = u1;
}

// ---- build A: per-chunk bucket histogram ----
__global__ __launch_bounds__(256) void hista_k(const int* __restrict__ ei, int E,
                                               int* __restrict__ blockhist) {
  __shared__ int h[NBUK];
  int tid = threadIdx.x;
  h[tid] = 0;
  __syncthreads();
  int lo = blockIdx.x * CHUNK, hi = min(lo + CHUNK, E);
  for (int e = lo + tid; e < hi; e += 256) {
    int t = ei[E + e];
    if ((unsigned)t < NN) atomicAdd(&h[t >> BSHIFT], 1);
  }
  __syncthreads();
  blockhist[(size_t)blockIdx.x * NBUK + tid] = h[tid];
}

// ---- build B: per-bucket exclusive scan over chunks + totals ----
__global__ __launch_bounds__(256) void scanb_k(int* __restrict__ blockhist, int nch,
                                               int* __restrict__ bukcnt) {
  __shared__ int sh[256];
  int b = blockIdx.x, t = threadIdx.x;
  int run = 0;
  for (int base = 0; base < nch; base += 256) {
    int c = base + t;
    int v = (c < nch) ? blockhist[(size_t)c * NBUK + b] : 0;
    sh[t] = v;
    __syncthreads();
    for (int o = 1; o < 256; o <<= 1) {
      int u = (t >= o) ? sh[t - o] : 0;
      __syncthreads();
      sh[t] += u;
      __syncthreads();
    }
    if (c < nch) blockhist[(size_t)c * NBUK + b] = run + sh[t] - v;
    int tot = sh[255];
    __syncthreads();
    run += tot;
  }
  if (t == 0) bukcnt[b] = run;
}

// ---- build C: scatter edges into packed bucket pairs (LDS cursors only) ----
__global__ __launch_bounds__(256) void scat_k(const int* __restrict__ ei, int E,
                                              const int* __restrict__ blockhist,
                                              unsigned* __restrict__ pairs) {
  __shared__ int wb[NBUK], cur[NBUK];
  int tid = threadIdx.x;
  wb[tid] = blockhist[(size_t)blockIdx.x * NBUK + tid];
  cur[tid] = 0;
  __syncthreads();
  int lo = blockIdx.x * CHUNK, hi = min(lo + CHUNK, E);
  for (int e = lo + tid; e < hi; e += 256) {
    int s = ei[e], t = ei[E + e];
    if ((unsigned)t >= NN) continue;
    if ((unsigned)s >= NN) s = 0;
    int b = t >> BSHIFT;
    int off = atomicAdd(&cur[b], 1);
    pairs[(size_t)b * BCAP + wb[b] + off] = ((unsigned)s << 9) | (unsigned)(t & 511);
  }
}

// ---- build D: per-bucket hist + scan -> rowstart/rowend + adj fill ----
__global__ __launch_bounds__(256) void bfill2_k(const unsigned* __restrict__ pairs,
                                                const int* __restrict__ bukcnt,
                                                int* __restrict__ rowstart,
                                                int* __restrict__ rowend,
                                                int* __restrict__ adj) {
  __shared__ int d[512];
  __shared__ int part[256];
  int b = blockIdx.x;
  int t = threadIdx.x;
  int base = b * BCAP, cnt = bukcnt[b];
  d[t] = 0; d[t + 256] = 0;
  __syncthreads();
  for (int p = base + t; p < base + cnt; p += 256)
    atomicAdd(&d[pairs[p] & 511], 1);
  __syncthreads();
  int d0 = d[2 * t], d1 = d[2 * t + 1];
  part[t] = d0 + d1;
  __syncthreads();
  for (int o = 1; o < 256; o <<= 1) {
    int u = (t >= o) ? part[t - o] : 0;
    __syncthreads();
    part[t] += u;
    __syncthreads();
  }
  int e0 = (t > 0) ? part[t - 1] : 0;
  int e1 = e0 + d0;
  d[2 * t] = e0;
  d[2 * t + 1] = e1;
  int n0 = (b << BSHIFT) + 2 * t;
  if (n0 < NN)     { rowstart[n0]     = base + e0; rowend[n0]     = base + e1; }
  if (n0 + 1 < NN) { rowstart[n0 + 1] = base + e1; rowend[n0 + 1] = base + e1 + d1; }
  __syncthreads();
  for (int p = base + t; p < base + cnt; p += 256) {
    unsigned pr = pairs[p];
    int pos = atomicAdd(&d[pr & 511], 1);
    adj[base + pos] = (int)(pr >> 9);
  }
}

// ---- gather-side mean aggregation, ushort4-vectorized ----
template<int K>
__global__ __launch_bounds__(256) void aggregate_bf(const unsigned short* __restrict__ xb,
                                                    const int* __restrict__ rowstart,
                                                    const int* __restrict__ rowend,
                                                    const int* __restrict__ adj,
                                                    float* __restrict__ agg) {
  constexpr int GL = K / 4;
  constexpr int NPB = 256 / GL;
  int lg = threadIdx.x & (GL - 1);
  int node = blockIdx.x * NPB + (threadIdx.x / GL);
  if (node >= NN) return;
  int s0 = rowstart[node], s1 = rowend[node];
  float4 a0 = {0,0,0,0}, a1 = {0,0,0,0}, a2 = {0,0,0,0}, a3 = {0,0,0,0};
  int e = s0;
  for (; e + 3 < s1; e += 4) {
    int i0 = adj[e], i1 = adj[e+1], i2 = adj[e+2], i3 = adj[e+3];
    ushort4 u0 = *(const ushort4*)(xb + (size_t)i0 * K + lg * 4);
    ushort4 u1 = *(const ushort4*)(xb + (size_t)i1 * K + lg * 4);
    ushort4 u2 = *(const ushort4*)(xb + (size_t)i2 * K + lg * 4);
    ushort4 u3 = *(const ushort4*)(xb + (size_t)i3 * K + lg * 4);
    a0.x += bf2f(u0.x); a0.y += bf2f(u0.y); a0.z += bf2f(u0.z); a0.w += bf2f(u0.w);
    a1.x += bf2f(u1.x); a1.y += bf2f(u1.y); a1.z += bf2f(u1.z); a1.w += bf2f(u1.w);
    a2.x += bf2f(u2.x); a2.y += bf2f(u2.y); a2.z += bf2f(u2.z); a2.w += bf2f(u2.w);
    a3.x += bf2f(u3.x); a3.y += bf2f(u3.y); a3.z += bf2f(u3.z); a3.w += bf2f(u3.w);
  }
  for (; e < s1; ++e) {
    ushort4 u = *(const ushort4*)(xb + (size_t)adj[e] * K + lg * 4);
    a0.x += bf2f(u.x); a0.y += bf2f(u.y); a0.z += bf2f(u.z); a0.w += bf2f(u.w);
  }
  float inv = 1.0f / fmaxf((float)(s1 - s0), 1.0f);
  float4 r;
  r.x = (a0.x + a1.x + a2.x + a3.x) * inv;
  r.y = (a0.y + a1.y + a2.y + a3.y) * inv;
  r.z = (a0.z + a1.z + a2.z + a3.z) * inv;
  r.w = (a0.w + a1.w + a2.w + a3.w) * inv;
  *(float4*)(agg + (size_t)node * K + lg * 4) = r;
}

// ---- MFMA dense layer; 64 rows/block, weights pre-split + staged in LDS ----
// BFIN: A-input is bf16 plane (inAb). FOUT: write f32 out. BFOUT: write bf16 outb.
template<int K, int C, bool SAGE, bool BNIN, bool BFIN, bool RELU, bool FOUT,
         bool BFOUT, bool STATS>
__global__ __launch_bounds__(256) void mfma_dense(const float* __restrict__ inA,
                                                  const unsigned short* __restrict__ inAb,
                                                  const float* __restrict__ inB,
                                                  const unsigned short* __restrict__ whiA,
                                                  const unsigned short* __restrict__ wloA,
                                                  const unsigned short* __restrict__ whiB,
                                                  const unsigned short* __restrict__ wloB,
                                                  const float* __restrict__ bias,
                                                  const float* __restrict__ coef,
                                                  float* __restrict__ out,
                                                  unsigned short* __restrict__ outb,
                                                  float* __restrict__ stats) {
  constexpr int KF = K / 32;
  constexpr int KC = K / 8;
  constexpr int SWZ = (KC < 8 ? KC : 8) - 1;
  __shared__ unsigned short swhiA[C * K], swloA[C * K];
  __shared__ unsigned short swhiB[SAGE ? C * K : 8], swloB[SAGE ? C * K : 8];
  __shared__ float ls[STATS ? C : 1], lq[STATS ? C : 1];

  int tid = threadIdx.x;
  for (int i = tid; i < C * KC; i += 256) {
    int col = i / KC, c = i % KC;
    int pos = col * KC + (c ^ (col & SWZ));
    ((short8*)swhiA)[pos] = ((const short8*)whiA)[i];
    ((short8*)swloA)[pos] = ((const short8*)wloA)[i];
    if (SAGE) {
      ((short8*)swhiB)[pos] = ((const short8*)whiB)[i];
      ((short8*)swloB)[pos] = ((const short8*)wloB)[i];
    }
  }
  if (STATS) {
    for (int i = tid; i < C; i += 256) { ls[i] = 0.f; lq[i] = 0.f; }
  }
  __syncthreads();

  int wid  = tid >> 6;
  int lane = tid & 63;
  int row0 = blockIdx.x * 64 + wid * 16;
  int r = lane & 15, g = lane >> 4;
  int arow = row0 + r; if (arow > NN - 1) arow = NN - 1;   // clamp tail reads
  int koff = g * 8;

  short8 ahi[KF], alo[KF];
  short8 a2hi[SAGE ? KF : 1], a2lo[SAGE ? KF : 1];
  #pragma unroll
  for (int kf = 0; kf < KF; ++kf) {
    const void* p = BFIN
        ? (const void*)(inAb + (size_t)arow * K + kf * 32 + koff)
        : (const void*)(inA  + (size_t)arow * K + kf * 32 + koff);
    load_split<BNIN, BFIN>(p, coef + kf * 32 + koff, coef + K + kf * 32 + koff,
                           ahi[kf], alo[kf]);
  }
  if (SAGE) {
    #pragma unroll
    for (int kf = 0; kf < KF; ++kf) {
      const float* p = inB + (size_t)arow * K + kf * 32 + koff;
      load_split<false, false>(p, nullptr, nullptr, a2hi[kf], a2lo[kf]);
    }
  }

  #pragma unroll
  for (int cf = 0; cf < C / 16; ++cf) {
    int col = cf * 16 + r;
    float bv = bias[col];
    f32x4 acc = {bv, bv, bv, bv};
    #pragma unroll
    for (int kf = 0; kf < KF; ++kf) {
      int c = kf * 4 + g;
      int pos = col * KC + (c ^ (col & SWZ));
      short8 whi = ((const short8*)swhiA)[pos];
      short8 wlo = ((const short8*)swloA)[pos];
      acc = MFMA_16x16x32(ahi[kf], whi, acc);
      acc = MFMA_16x16x32(ahi[kf], wlo, acc);
      acc = MFMA_16x16x32(alo[kf], whi, acc);
      if (SAGE) {
        short8 vhi = ((const short8*)swhiB)[pos];
        short8 vlo = ((const short8*)swloB)[pos];
        acc = MFMA_16x16x32(a2hi[kf], vhi, acc);
        acc = MFMA_16x16x32(a2hi[kf], vlo, acc);
        acc = MFMA_16x16x32(a2lo[kf], vhi, acc);
      }
    }
    if (STATS) {
      float s = 0.f, q = 0.f;
      #pragma unroll
      for (int j = 0; j < 4; ++j) {
        if (row0 + g * 4 + j < NN) {
          float v = acc[j];
          s += v; q += v * v;
        }
      }
      s += __shfl_xor(s, 16, 64); s += __shfl_xor(s, 32, 64);
      q += __shfl_xor(q, 16, 64); q += __shfl_xor(q, 32, 64);
      if (g == 0) { atomicAdd(&ls[col], s); atomicAdd(&lq[col], q); }
    }
    #pragma unroll
    for (int j = 0; j < 4; ++j) {
      int orow = row0 + g * 4 + j;
      if (orow < NN) {
        float v = acc[j];
        if (RELU) v = fmaxf(v, 0.f);
        if (FOUT)  out[(size_t)orow * C + col] = v;
        if (BFOUT) outb[(size_t)orow * C + col] = f2bf(v);
      }
    }
  }
  if (STATS) {
    __syncthreads();
    float* sl = stats + (size_t)(blockIdx.x & (NSLOT - 1)) * 2 * C;
    for (int i = tid; i < C; i += 256) {
      atomicAdd(&sl[i], ls[i]);
      atomicAdd(&sl[C + i], lq[i]);
    }
  }
}

// ---- slotted stats -> affine coefs ----
__global__ void bncoef(const float* __restrict__ stats, const float* __restrict__ g,
                       const float* __restrict__ b, float* __restrict__ coef, int C) {
  int j = threadIdx.x;
  if (j >= C) return;
  float s = 0.f, q = 0.f;
  for (int sl = 0; sl < NSLOT; ++sl) {
    s += stats[(size_t)sl * 2 * C + j];
    q += stats[(size_t)sl * 2 * C + C + j];
  }
  float mu  = s * (1.0f / NN);
  float var = q * (1.0f / NN) - mu * mu;
  float a = g[j] * rsqrtf(var + EPS);
  coef[j] = a;
  coef[C + j] = b[j] - mu * a;
}

// ---- final: out[i] = sum_j relu(bf2f(z2b[i][j])*a+c) * fc3w[j] + fc3b ----
__global__ __launch_bounds__(256) void final_k(const unsigned short* __restrict__ z2b,
                                               const float* __restrict__ coef,
                                               const float* __restrict__ fc3w,
                                               const float* __restrict__ fc3b,
                                               float* __restrict__ out) {
  int t = blockIdx.x * 256 + threadIdx.x;
  int i = t >> 6;
  int j = t & 63;
  if (i >= NN) return;
  float v = bf2f(z2b[(size_t)i * 64 + j]);
  float p = fmaxf(v * coef[j] + coef[64 + j], 0.f) * fc3w[j];
  #pragma unroll
  for (int o = 32; o > 0; o >>= 1) p += __shfl_xor(p, o, 64);
  if (j == 0) out[i] = p + fc3b[0];
}

extern "C" void kernel_launch(void* const* d_in, const int* in_sizes, int n_in,
                              void* d_out, int out_size, void* d_ws, size_t ws_size,
                              hipStream_t stream) {
  const float* x     = (const float*)d_in[0];
  const int*   ei    = (const int*)d_in[1];
  const float* w_l1  = (const float*)d_in[2];
  const float* b_l1  = (const float*)d_in[3];
  const float* w_r1  = (const float*)d_in[4];
  const float* w_l2  = (const float*)d_in[5];
  const float* b_l2  = (const float*)d_in[6];
  const float* w_r2  = (const float*)d_in[7];
  const float* fc1_w = (const float*)d_in[8];
  const float* fc1_b = (const float*)d_in[9];
  const float* bn1_g = (const float*)d_in[10];
  const float* bn1_b = (const float*)d_in[11];
  const float* fc2_w = (const float*)d_in[12];
  const float* fc2_b = (const float*)d_in[13];
  const float* bn2_g = (const float*)d_in[14];
  const float* bn2_b = (const float*)d_in[15];
  const float* fc3_w = (const float*)d_in[16];
  const float* fc3_b = (const float*)d_in[17];

  const int E = in_sizes[1] / 2;

  float* ws       = (float*)d_ws;
  int*   rowstart = (int*)(ws + OFF_ROWST);
  int*   rowend   = (int*)(ws + OFF_ROWEN);
  int*   adj      = (int*)(ws + OFF_ADJ);
  float* agg1     = ws + OFF_AGG1;
  float* agg2     = ws + OFF_AGG2;
  unsigned short* xb  = (unsigned short*)(ws + OFF_XB);
  unsigned short* h1b = (unsigned short*)(ws + OFF_H1B);
  unsigned short* z1b = (unsigned short*)(ws + OFF_Z1B);
  unsigned short* z2b = (unsigned short*)(ws + OFF_Z2B);
  int*   bukcnt   = (int*)(ws + OFF_BUKCNT);
  float* stats1   = ws + OFF_STATS1;
  float* stats2   = ws + OFF_STATS2;
  float* coef1    = ws + OFF_COEF1;
  float* coef2    = ws + OFF_COEF2;
  unsigned* pairs = (unsigned*)(ws + OFF_PAIRS);
  int*   bhist    = (int*)(ws + OFF_BHIST);
  unsigned short* wspl = (unsigned short*)(ws + OFF_WSPL);

  float* outv = (float*)d_out;             // [NN]
  float* h1   = outv + NN;                 // [NN,64]
  float* h2   = h1 + (size_t)NN * 64;      // [NN,64]

  hipMemsetAsync(ws + ZERO_START, 0, ZERO_INTS * sizeof(float), stream);

  // one-shot weight splits (hi/lo bf16 planes)
  WsplitArgs wa;
  wa.src[0] = w_l1;  wa.dhi[0] = wspl + WL1_HI; wa.dlo[0] = wspl + WL1_LO; wa.n[0] = 64 * 32;
  wa.src[1] = w_r1;  wa.dhi[1] = wspl + WR1_HI; wa.dlo[1] = wspl + WR1_LO; wa.n[1] = 64 * 32;
  wa.src[2] = w_l2;  wa.dhi[2] = wspl + WL2_HI; wa.dlo[2] = wspl + WL2_LO; wa.n[2] = 64 * 64;
  wa.src[3] = w_r2;  wa.dhi[3] = wspl + WR2_HI; wa.dlo[3] = wspl + WR2_LO; wa.n[3] = 64 * 64;
  wa.src[4] = fc1_w; wa.dhi[4] = wspl + F1_HI;  wa.dlo[4] = wspl + F1_LO;  wa.n[4] = 128 * 64;
  wa.src[5] = fc2_w; wa.dhi[5] = wspl + F2_HI;  wa.dlo[5] = wspl + F2_LO;  wa.n[5] = 64 * 128;
  wsplit_k<<<dim3(8, 6), 256, 0, stream>>>(wa);

  // bf16 copy of x for cheap gathering
  cvt_bf_k<<<(NN * 32 / 8 + 255) / 256, 256, 0, stream>>>(x, xb, NN * 32 / 8);

  // CSR build — deterministic partition
  const int NCH = (E + CHUNK - 1) / CHUNK;
  hista_k<<<NCH, 256, 0, stream>>>(ei, E, bhist);
  scanb_k<<<NBUK, 256, 0, stream>>>(bhist, NCH, bukcnt);
  scat_k<<<NCH, 256, 0, stream>>>(ei, E, bhist, pairs);
  bfill2_k<<<NBUK, 256, 0, stream>>>(pairs, bukcnt, rowstart, rowend, adj);

  const int MB = (NN + 63) / 64;   // 64 rows per block (r15 config)

  // layer 1
  aggregate_bf<32><<<(NN + 31) / 32, 256, 0, stream>>>(xb, rowstart, rowend, adj, agg1);
  mfma_dense<32, 64, true, false, false, true, true, true, false><<<MB, 256, 0, stream>>>(
      agg1, nullptr, x, wspl + WL1_HI, wspl + WL1_LO, wspl + WR1_HI, wspl + WR1_LO,
      b_l1, nullptr, h1, h1b, nullptr);

  // layer 2
  aggregate_bf<64><<<(NN + 15) / 16, 256, 0, stream>>>(h1b, rowstart, rowend, adj, agg2);
  mfma_dense<64, 64, true, false, false, true, true, false, false><<<MB, 256, 0, stream>>>(
      agg2, nullptr, h1, wspl + WL2_HI, wspl + WL2_LO, wspl + WR2_HI, wspl + WR2_LO,
      b_l2, nullptr, h2, nullptr, nullptr);

  // fc1 -> z1b (bf16, pre-BN) with fused slotted stats
  mfma_dense<64, 128, false, false, false, false, false, true, true><<<MB, 256, 0, stream>>>(
      h2, nullptr, nullptr, wspl + F1_HI, wspl + F1_LO, nullptr, nullptr,
      fc1_b, nullptr, nullptr, z1b, stats1);
  bncoef<<<1, 128, 0, stream>>>(stats1, bn1_g, bn1_b, coef1, 128);

  // fc2 (bf16 input, fused bn1+relu) -> z2b (bf16, pre-BN) with fused stats
  mfma_dense<128, 64, false, true, true, false, false, true, true><<<MB, 256, 0, stream>>>(
      nullptr, z1b, nullptr, wspl + F2_HI, wspl + F2_LO, nullptr, nullptr,
      fc2_b, coef1, nullptr, z2b, stats2);
  bncoef<<<1, 64, 0, stream>>>(stats2, bn2_g, bn2_b, coef2, 64);

  // bn2 + relu + fc3 fused
  final_k<<<(NN * 64 + 255) / 256, 256, 0, stream>>>(z2b, coef2, fc3_w, fc3_b, outv);
}

// Round 18
// 237.709 us; speedup vs baseline: 1.0531x; 1.0005x over previous
//
#include <hip/hip_runtime.h>

#define NN 100000
#define EPS 1e-5f

// ---- workspace layout (4-byte units), ~83MB total ----
static const size_t OFF_ROWST  = 0;           // rowstart [100k]
static const size_t OFF_ROWEN  = 100000;      // rowend   [100k]
static const size_t OFF_ADJ    = 200000;      // adj [256*10496] -> 2,886,976
static const size_t OFF_AGG1   = 2886976;     // N*32 f32 -> 6,086,976
static const size_t OFF_AGG2   = 6086976;     // N*64 f32 -> 12,486,976
static const size_t OFF_PAIRS  = 2886976;     // u32 aliases agg (dead before agg1)
static const size_t OFF_XB     = 12486976;    // N*32 bf16 -> 14,086,976
static const size_t OFF_Z1B    = 0;           // N*128 bf16 (dead by fc1's input h2)
static const size_t OFF_H1B    = 14086976;    // N*64 bf16 -> 17,286,976
static const size_t OFF_Z2B    = 14086976;    // aliases h1b (dead before fc2)
static const size_t OFF_WSPL   = 20487000;    // 57,344 ushorts -> 20,515,672
static const size_t OFF_BUKCNT = 20515712;    // 256 ints
static const size_t OFF_STATS1 = 20515968;    // 128 slots * 256 -> 20,548,736
static const size_t OFF_STATS2 = 20548736;    // 128 slots * 128 -> 20,565,120
static const size_t OFF_COEF1  = 20565120;    // 256
static const size_t OFF_COEF2  = 20565376;    // 128
static const size_t OFF_BHIST  = 20565504;    // NCH*256 ints -> 20,765,696
static const size_t ZERO_START = 20515968;    // slotted stats only
static const size_t ZERO_INTS  = 49152;

#define NSLOT 128

// split-weight plane offsets (ushort units within WSPL)
#define WL1_HI 0
#define WL1_LO 2048
#define WR1_HI 4096
#define WR1_LO 6144
#define WL2_HI 8192
#define WL2_LO 12288
#define WR2_HI 16384
#define WR2_LO 20480
#define F1_HI  24576
#define F1_LO  32768
#define F2_HI  40960
#define F2_LO  49152

#define NBUK 256
#define BSHIFT 9
#define BCAP 10496
#define CHUNK 2048

typedef __attribute__((ext_vector_type(8))) short short8;
typedef __attribute__((ext_vector_type(4))) float f32x4;

#define MFMA_16x16x32(a, b, c) __builtin_amdgcn_mfma_f32_16x16x32_bf16(a, b, c, 0, 0, 0)

__device__ inline unsigned short f2bf(float f) {
  unsigned u = __builtin_bit_cast(unsigned, f);
  unsigned r = (u + 0x7fffu + ((u >> 16) & 1u)) >> 16;
  return (unsigned short)r;
}
__device__ inline float bf2f(unsigned short h) {
  unsigned u = ((unsigned)h) << 16;
  return __builtin_bit_cast(float, u);
}

// load 8 contiguous values (f32 or bf16 per BFIN; optional BN+relu), split hi/lo bf16
template<bool BNIN, bool BFIN>
__device__ inline void load_split(const void* __restrict__ p,
                                  const float* __restrict__ ca,
                                  const float* __restrict__ cc,
                                  short8& hi, short8& lo) {
  #pragma unroll
  for (int j = 0; j < 8; ++j) {
    float v = BFIN ? bf2f(((const unsigned short*)p)[j]) : ((const float*)p)[j];
    if (BNIN) v = fmaxf(v * ca[j] + cc[j], 0.f);
    unsigned short h = f2bf(v);
    hi[j] = (short)h;
    lo[j] = (short)f2bf(v - bf2f(h));
  }
}

// ---- one-shot: split all 6 weight matrices into hi/lo bf16 planes ----
struct WsplitArgs {
  const float* src[6];
  unsigned short* dhi[6];
  unsigned short* dlo[6];
  int n[6];
};
__global__ __launch_bounds__(256) void wsplit_k(WsplitArgs a) {
  int m = blockIdx.y;
  int n = a.n[m];
  for (int i = blockIdx.x * 256 + threadIdx.x; i < n; i += gridDim.x * 256) {
    float v = a.src[m][i];
    unsigned short h = f2bf(v);
    a.dhi[m][i] = h;
    a.dlo[m][i] = f2bf(v - bf2f(h));
  }
}

// ---- convert f32 plane -> bf16 plane ----
__global__ __launch_bounds__(256) void cvt_bf_k(const float* __restrict__ in,
                                                unsigned short* __restrict__ out,
                                                int n8) {
  int t = blockIdx.x * 256 + threadIdx.x;
  if (t >= n8) return;
  const float4* p = (const float4*)(in + (size_t)t * 8);
  float4 a = p[0], b = p[1];
  ushort4 u0, u1;
  u0.x = f2bf(a.x); u0.y = f2bf(a.y); u0.z = f2bf(a.z); u0.w = f2bf(a.w);
  u1.x = f2bf(b.x); u1.y = f2bf(b.y); u1.z = f2bf(b.z); u1.w = f2bf(b.w);
  ((ushort4*)(out + (size_t)t * 8))[0] = u0;
  ((ushort4*)(out + (size_t)t * 8))[1] = u1;
}

// ---- build A: per-chunk bucket histogram ----
__global__ __launch_bounds__(256) void hista_k(const int* __restrict__ ei, int E,
                                               int* __restrict__ blockhist) {
  __shared__ int h[NBUK];
  int tid = threadIdx.x;
  h[tid] = 0;
  __syncthreads();
  int lo = blockIdx.x * CHUNK, hi = min(lo + CHUNK, E);
  for (int e = lo + tid; e < hi; e += 256) {
    int t = ei[E + e];
    if ((unsigned)t < NN) atomicAdd(&h[t >> BSHIFT], 1);
  }
  __syncthreads();
  blockhist[(size_t)blockIdx.x * NBUK + tid] = h[tid];
}

// ---- build B: per-bucket exclusive scan over chunks + totals ----
__global__ __launch_bounds__(256) void scanb_k(int* __restrict__ blockhist, int nch,
                                               int* __restrict__ bukcnt) {
  __shared__ int sh[256];
  int b = blockIdx.x, t = threadIdx.x;
  int run = 0;
  for (int base = 0; base < nch; base += 256) {
    int c = base + t;
    int v = (c < nch) ? blockhist[(size_t)c * NBUK + b] : 0;
    sh[t] = v;
    __syncthreads();
    for (int o = 1; o < 256; o <<= 1) {
      int u = (t >= o) ? sh[t - o] : 0;
      __syncthreads();
      sh[t] += u;
      __syncthreads();
    }
    if (c < nch) blockhist[(size_t)c * NBUK + b] = run + sh[t] - v;
    int tot = sh[255];
    __syncthreads();
    run += tot;
  }
  if (t == 0) bukcnt[b] = run;
}

// ---- build C: scatter edges into packed bucket pairs (LDS cursors only) ----
__global__ __launch_bounds__(256) void scat_k(const int* __restrict__ ei, int E,
                                              const int* __restrict__ blockhist,
                                              unsigned* __restrict__ pairs) {
  __shared__ int wb[NBUK], cur[NBUK];
  int tid = threadIdx.x;
  wb[tid] = blockhist[(size_t)blockIdx.x * NBUK + tid];
  cur[tid] = 0;
  __syncthreads();
  int lo = blockIdx.x * CHUNK, hi = min(lo + CHUNK, E);
  for (int e = lo + tid; e < hi; e += 256) {
    int s = ei[e], t = ei[E + e];
    if ((unsigned)t >= NN) continue;
    if ((unsigned)s >= NN) s = 0;
    int b = t >> BSHIFT;
    int off = atomicAdd(&cur[b], 1);
    pairs[(size_t)b * BCAP + wb[b] + off] = ((unsigned)s << 9) | (unsigned)(t & 511);
  }
}

// ---- build D: per-bucket hist + scan -> rowstart/rowend + adj fill ----
__global__ __launch_bounds__(256) void bfill2_k(const unsigned* __restrict__ pairs,
                                                const int* __restrict__ bukcnt,
                                                int* __restrict__ rowstart,
                                                int* __restrict__ rowend,
                                                int* __restrict__ adj) {
  __shared__ int d[512];
  __shared__ int part[256];
  int b = blockIdx.x;
  int t = threadIdx.x;
  int base = b * BCAP, cnt = bukcnt[b];
  d[t] = 0; d[t + 256] = 0;
  __syncthreads();
  for (int p = base + t; p < base + cnt; p += 256)
    atomicAdd(&d[pairs[p] & 511], 1);
  __syncthreads();
  int d0 = d[2 * t], d1 = d[2 * t + 1];
  part[t] = d0 + d1;
  __syncthreads();
  for (int o = 1; o < 256; o <<= 1) {
    int u = (t >= o) ? part[t - o] : 0;
    __syncthreads();
    part[t] += u;
    __syncthreads();
  }
  int e0 = (t > 0) ? part[t - 1] : 0;
  int e1 = e0 + d0;
  d[2 * t] = e0;
  d[2 * t + 1] = e1;
  int n0 = (b << BSHIFT) + 2 * t;
  if (n0 < NN)     { rowstart[n0]     = base + e0; rowend[n0]     = base + e1; }
  if (n0 + 1 < NN) { rowstart[n0 + 1] = base + e1; rowend[n0 + 1] = base + e1 + d1; }
  __syncthreads();
  for (int p = base + t; p < base + cnt; p += 256) {
    unsigned pr = pairs[p];
    int pos = atomicAdd(&d[pr & 511], 1);
    adj[base + pos] = (int)(pr >> 9);
  }
}

// ---- gather-side mean aggregation, ushort4-vectorized ----
template<int K>
__global__ __launch_bounds__(256) void aggregate_bf(const unsigned short* __restrict__ xb,
                                                    const int* __restrict__ rowstart,
                                                    const int* __restrict__ rowend,
                                                    const int* __restrict__ adj,
                                                    float* __restrict__ agg) {
  constexpr int GL = K / 4;
  constexpr int NPB = 256 / GL;
  int lg = threadIdx.x & (GL - 1);
  int node = blockIdx.x * NPB + (threadIdx.x / GL);
  if (node >= NN) return;
  int s0 = rowstart[node], s1 = rowend[node];
  float4 a0 = {0,0,0,0}, a1 = {0,0,0,0}, a2 = {0,0,0,0}, a3 = {0,0,0,0};
  int e = s0;
  for (; e + 3 < s1; e += 4) {
    int i0 = adj[e], i1 = adj[e+1], i2 = adj[e+2], i3 = adj[e+3];
    ushort4 u0 = *(const ushort4*)(xb + (size_t)i0 * K + lg * 4);
    ushort4 u1 = *(const ushort4*)(xb + (size_t)i1 * K + lg * 4);
    ushort4 u2 = *(const ushort4*)(xb + (size_t)i2 * K + lg * 4);
    ushort4 u3 = *(const ushort4*)(xb + (size_t)i3 * K + lg * 4);
    a0.x += bf2f(u0.x); a0.y += bf2f(u0.y); a0.z += bf2f(u0.z); a0.w += bf2f(u0.w);
    a1.x += bf2f(u1.x); a1.y += bf2f(u1.y); a1.z += bf2f(u1.z); a1.w += bf2f(u1.w);
    a2.x += bf2f(u2.x); a2.y += bf2f(u2.y); a2.z += bf2f(u2.z); a2.w += bf2f(u2.w);
    a3.x += bf2f(u3.x); a3.y += bf2f(u3.y); a3.z += bf2f(u3.z); a3.w += bf2f(u3.w);
  }
  for (; e < s1; ++e) {
    ushort4 u = *(const ushort4*)(xb + (size_t)adj[e] * K + lg * 4);
    a0.x += bf2f(u.x); a0.y += bf2f(u.y); a0.z += bf2f(u.z); a0.w += bf2f(u.w);
  }
  float inv = 1.0f / fmaxf((float)(s1 - s0), 1.0f);
  float4 r;
  r.x = (a0.x + a1.x + a2.x + a3.x) * inv;
  r.y = (a0.y + a1.y + a2.y + a3.y) * inv;
  r.z = (a0.z + a1.z + a2.z + a3.z) * inv;
  r.w = (a0.w + a1.w + a2.w + a3.w) * inv;
  *(float4*)(agg + (size_t)node * K + lg * 4) = r;
}

// ---- MFMA dense layer; 512 threads = 8 waves sharing one LDS weight copy ----
// 128 rows/block, tiles run in PARALLEL waves (r16 serialized them — that failed).
// BFIN: A-input bf16 plane. FOUT: f32 out. BFOUT: bf16 outb. STATS: slotted col stats.
template<int K, int C, bool SAGE, bool BNIN, bool BFIN, bool RELU, bool FOUT,
         bool BFOUT, bool STATS>
__global__ __launch_bounds__(512) void mfma_dense(const float* __restrict__ inA,
                                                  const unsigned short* __restrict__ inAb,
                                                  const float* __restrict__ inB,
                                                  const unsigned short* __restrict__ whiA,
                                                  const unsigned short* __restrict__ wloA,
                                                  const unsigned short* __restrict__ whiB,
                                                  const unsigned short* __restrict__ wloB,
                                                  const float* __restrict__ bias,
                                                  const float* __restrict__ coef,
                                                  float* __restrict__ out,
                                                  unsigned short* __restrict__ outb,
                                                  float* __restrict__ stats) {
  constexpr int KF = K / 32;
  constexpr int KC = K / 8;
  constexpr int SWZ = (KC < 8 ? KC : 8) - 1;
  __shared__ unsigned short swhiA[C * K], swloA[C * K];
  __shared__ unsigned short swhiB[SAGE ? C * K : 8], swloB[SAGE ? C * K : 8];
  __shared__ float ls[STATS ? C : 1], lq[STATS ? C : 1];

  int tid = threadIdx.x;
  for (int i = tid; i < C * KC; i += 512) {
    int col = i / KC, c = i % KC;
    int pos = col * KC + (c ^ (col & SWZ));
    ((short8*)swhiA)[pos] = ((const short8*)whiA)[i];
    ((short8*)swloA)[pos] = ((const short8*)wloA)[i];
    if (SAGE) {
      ((short8*)swhiB)[pos] = ((const short8*)whiB)[i];
      ((short8*)swloB)[pos] = ((const short8*)wloB)[i];
    }
  }
  if (STATS) {
    for (int i = tid; i < C; i += 512) { ls[i] = 0.f; lq[i] = 0.f; }
  }
  __syncthreads();

  int wid  = tid >> 6;                     // 0..7 — 8 parallel waves, 16 rows each
  int lane = tid & 63;
  int row0 = blockIdx.x * 128 + wid * 16;
  int r = lane & 15, g = lane >> 4;
  int arow = row0 + r; if (arow > NN - 1) arow = NN - 1;   // clamp tail reads
  int koff = g * 8;

  short8 ahi[KF], alo[KF];
  short8 a2hi[SAGE ? KF : 1], a2lo[SAGE ? KF : 1];
  #pragma unroll
  for (int kf = 0; kf < KF; ++kf) {
    const void* p = BFIN
        ? (const void*)(inAb + (size_t)arow * K + kf * 32 + koff)
        : (const void*)(inA  + (size_t)arow * K + kf * 32 + koff);
    load_split<BNIN, BFIN>(p, coef + kf * 32 + koff, coef + K + kf * 32 + koff,
                           ahi[kf], alo[kf]);
  }
  if (SAGE) {
    #pragma unroll
    for (int kf = 0; kf < KF; ++kf) {
      const float* p = inB + (size_t)arow * K + kf * 32 + koff;
      load_split<false, false>(p, nullptr, nullptr, a2hi[kf], a2lo[kf]);
    }
  }

  #pragma unroll
  for (int cf = 0; cf < C / 16; ++cf) {
    int col = cf * 16 + r;
    float bv = bias[col];
    f32x4 acc = {bv, bv, bv, bv};
    #pragma unroll
    for (int kf = 0; kf < KF; ++kf) {
      int c = kf * 4 + g;
      int pos = col * KC + (c ^ (col & SWZ));
      short8 whi = ((const short8*)swhiA)[pos];
      short8 wlo = ((const short8*)swloA)[pos];
      acc = MFMA_16x16x32(ahi[kf], whi, acc);
      acc = MFMA_16x16x32(ahi[kf], wlo, acc);
      acc = MFMA_16x16x32(alo[kf], whi, acc);
      if (SAGE) {
        short8 vhi = ((const short8*)swhiB)[pos];
        short8 vlo = ((const short8*)swloB)[pos];
        acc = MFMA_16x16x32(a2hi[kf], vhi, acc);
        acc = MFMA_16x16x32(a2hi[kf], vlo, acc);
        acc = MFMA_16x16x32(a2lo[kf], vhi, acc);
      }
    }
    if (STATS) {
      float s = 0.f, q = 0.f;
      #pragma unroll
      for (int j = 0; j < 4; ++j) {
        if (row0 + g * 4 + j < NN) {
          float v = acc[j];
          s += v; q += v * v;
        }
      }
      s += __shfl_xor(s, 16, 64); s += __shfl_xor(s, 32, 64);
      q += __shfl_xor(q, 16, 64); q += __shfl_xor(q, 32, 64);
      if (g == 0) { atomicAdd(&ls[col], s); atomicAdd(&lq[col], q); }
    }
    #pragma unroll
    for (int j = 0; j < 4; ++j) {
      int orow = row0 + g * 4 + j;
      if (orow < NN) {
        float v = acc[j];
        if (RELU) v = fmaxf(v, 0.f);
        if (FOUT)  out[(size_t)orow * C + col] = v;
        if (BFOUT) outb[(size_t)orow * C + col] = f2bf(v);
      }
    }
  }
  if (STATS) {
    __syncthreads();
    float* sl = stats + (size_t)(blockIdx.x & (NSLOT - 1)) * 2 * C;
    for (int i = tid; i < C; i += 512) {
      atomicAdd(&sl[i], ls[i]);
      atomicAdd(&sl[C + i], lq[i]);
    }
  }
}

// ---- slotted stats -> affine coefs ----
__global__ void bncoef(const float* __restrict__ stats, const float* __restrict__ g,
                       const float* __restrict__ b, float* __restrict__ coef, int C) {
  int j = threadIdx.x;
  if (j >= C) return;
  float s = 0.f, q = 0.f;
  for (int sl = 0; sl < NSLOT; ++sl) {
    s += stats[(size_t)sl * 2 * C + j];
    q += stats[(size_t)sl * 2 * C + C + j];
  }
  float mu  = s * (1.0f / NN);
  float var = q * (1.0f / NN) - mu * mu;
  float a = g[j] * rsqrtf(var + EPS);
  coef[j] = a;
  coef[C + j] = b[j] - mu * a;
}

// ---- final: out[i] = sum_j relu(bf2f(z2b[i][j])*a+c) * fc3w[j] + fc3b ----
__global__ __launch_bounds__(256) void final_k(const unsigned short* __restrict__ z2b,
                                               const float* __restrict__ coef,
                                               const float* __restrict__ fc3w,
                                               const float* __restrict__ fc3b,
                                               float* __restrict__ out) {
  int t = blockIdx.x * 256 + threadIdx.x;
  int i = t >> 6;
  int j = t & 63;
  if (i >= NN) return;
  float v = bf2f(z2b[(size_t)i * 64 + j]);
  float p = fmaxf(v * coef[j] + coef[64 + j], 0.f) * fc3w[j];
  #pragma unroll
  for (int o = 32; o > 0; o >>= 1) p += __shfl_xor(p, o, 64);
  if (j == 0) out[i] = p + fc3b[0];
}

extern "C" void kernel_launch(void* const* d_in, const int* in_sizes, int n_in,
                              void* d_out, int out_size, void* d_ws, size_t ws_size,
                              hipStream_t stream) {
  const float* x     = (const float*)d_in[0];
  const int*   ei    = (const int*)d_in[1];
  const float* w_l1  = (const float*)d_in[2];
  const float* b_l1  = (const float*)d_in[3];
  const float* w_r1  = (const float*)d_in[4];
  const float* w_l2  = (const float*)d_in[5];
  const float* b_l2  = (const float*)d_in[6];
  const float* w_r2  = (const float*)d_in[7];
  const float* fc1_w = (const float*)d_in[8];
  const float* fc1_b = (const float*)d_in[9];
  const float* bn1_g = (const float*)d_in[10];
  const float* bn1_b = (const float*)d_in[11];
  const float* fc2_w = (const float*)d_in[12];
  const float* fc2_b = (const float*)d_in[13];
  const float* bn2_g = (const float*)d_in[14];
  const float* bn2_b = (const float*)d_in[15];
  const float* fc3_w = (const float*)d_in[16];
  const float* fc3_b = (const float*)d_in[17];

  const int E = in_sizes[1] / 2;

  float* ws       = (float*)d_ws;
  int*   rowstart = (int*)(ws + OFF_ROWST);
  int*   rowend   = (int*)(ws + OFF_ROWEN);
  int*   adj      = (int*)(ws + OFF_ADJ);
  float* agg1     = ws + OFF_AGG1;
  float* agg2     = ws + OFF_AGG2;
  unsigned short* xb  = (unsigned short*)(ws + OFF_XB);
  unsigned short* h1b = (unsigned short*)(ws + OFF_H1B);
  unsigned short* z1b = (unsigned short*)(ws + OFF_Z1B);
  unsigned short* z2b = (unsigned short*)(ws + OFF_Z2B);
  int*   bukcnt   = (int*)(ws + OFF_BUKCNT);
  float* stats1   = ws + OFF_STATS1;
  float* stats2   = ws + OFF_STATS2;
  float* coef1    = ws + OFF_COEF1;
  float* coef2    = ws + OFF_COEF2;
  unsigned* pairs = (unsigned*)(ws + OFF_PAIRS);
  int*   bhist    = (int*)(ws + OFF_BHIST);
  unsigned short* wspl = (unsigned short*)(ws + OFF_WSPL);

  float* outv = (float*)d_out;             // [NN]
  float* h1   = outv + NN;                 // [NN,64]
  float* h2   = h1 + (size_t)NN * 64;      // [NN,64]

  hipMemsetAsync(ws + ZERO_START, 0, ZERO_INTS * sizeof(float), stream);

  // one-shot weight splits (hi/lo bf16 planes)
  WsplitArgs wa;
  wa.src[0] = w_l1;  wa.dhi[0] = wspl + WL1_HI; wa.dlo[0] = wspl + WL1_LO; wa.n[0] = 64 * 32;
  wa.src[1] = w_r1;  wa.dhi[1] = wspl + WR1_HI; wa.dlo[1] = wspl + WR1_LO; wa.n[1] = 64 * 32;
  wa.src[2] = w_l2;  wa.dhi[2] = wspl + WL2_HI; wa.dlo[2] = wspl + WL2_LO; wa.n[2] = 64 * 64;
  wa.src[3] = w_r2;  wa.dhi[3] = wspl + WR2_HI; wa.dlo[3] = wspl + WR2_LO; wa.n[3] = 64 * 64;
  wa.src[4] = fc1_w; wa.dhi[4] = wspl + F1_HI;  wa.dlo[4] = wspl + F1_LO;  wa.n[4] = 128 * 64;
  wa.src[5] = fc2_w; wa.dhi[5] = wspl + F2_HI;  wa.dlo[5] = wspl + F2_LO;  wa.n[5] = 64 * 128;
  wsplit_k<<<dim3(8, 6), 256, 0, stream>>>(wa);

  // bf16 copy of x for cheap gathering
  cvt_bf_k<<<(NN * 32 / 8 + 255) / 256, 256, 0, stream>>>(x, xb, NN * 32 / 8);

  // CSR build — deterministic partition
  const int NCH = (E + CHUNK - 1) / CHUNK;
  hista_k<<<NCH, 256, 0, stream>>>(ei, E, bhist);
  scanb_k<<<NBUK, 256, 0, stream>>>(bhist, NCH, bukcnt);
  scat_k<<<NCH, 256, 0, stream>>>(ei, E, bhist, pairs);
  bfill2_k<<<NBUK, 256, 0, stream>>>(pairs, bukcnt, rowstart, rowend, adj);

  const int MB = (NN + 127) / 128;   // 128 rows per block, 8 parallel waves

  // layer 1
  aggregate_bf<32><<<(NN + 31) / 32, 256, 0, stream>>>(xb, rowstart, rowend, adj, agg1);
  mfma_dense<32, 64, true, false, false, true, true, true, false><<<MB, 512, 0, stream>>>(
      agg1, nullptr, x, wspl + WL1_HI, wspl + WL1_LO, wspl + WR1_HI, wspl + WR1_LO,
      b_l1, nullptr, h1, h1b, nullptr);

  // layer 2
  aggregate_bf<64><<<(NN + 15) / 16, 256, 0, stream>>>(h1b, rowstart, rowend, adj, agg2);
  mfma_dense<64, 64, true, false, false, true, true, false, false><<<MB, 512, 0, stream>>>(
      agg2, nullptr, h1, wspl + WL2_HI, wspl + WL2_LO, wspl + WR2_HI, wspl + WR2_LO,
      b_l2, nullptr, h2, nullptr, nullptr);

  // fc1 -> z1b (bf16, pre-BN) with fused slotted stats
  mfma_dense<64, 128, false, false, false, false, false, true, true><<<MB, 512, 0, stream>>>(
      h2, nullptr, nullptr, wspl + F1_HI, wspl + F1_LO, nullptr, nullptr,
      fc1_b, nullptr, nullptr, z1b, stats1);
  bncoef<<<1, 128, 0, stream>>>(stats1, bn1_g, bn1_b, coef1, 128);

  // fc2 (bf16 input, fused bn1+relu) -> z2b (bf16, pre-BN) with fused stats
  mfma_dense<128, 64, false, true, true, false, false, true, true><<<MB, 512, 0, stream>>>(
      nullptr, z1b, nullptr, wspl + F2_HI, wspl + F2_LO, nullptr, nullptr,
      fc2_b, coef1, nullptr, z2b, stats2);
  bncoef<<<1, 64, 0, stream>>>(stats2, bn2_g, bn2_b, coef2, 64);

  // bn2 + relu + fc3 fused
  final_k<<<(NN * 64 + 255) / 256, 256, 0, stream>>>(z2b, coef2, fc3_w, fc3_b, outv);
}